// Round 6
// baseline (996.755 us; speedup 1.0000x reference)
//
#include <hip/hip_runtime.h>
#include <hip/hip_bf16.h>

#define N_NODES  100000
#define N_EDGES  300000
#define FEAT     256
#define N_GRAPHS 500
#define N_LAYERS 6
#define SCAN_B   1024

typedef __attribute__((ext_vector_type(8))) short v8s;   // 8 x bf16 bits (4 VGPRs)
typedef __attribute__((ext_vector_type(4))) float v4f;   // MFMA accumulator

__device__ __forceinline__ unsigned short f2bf(float f) {
    unsigned u = __float_as_uint(f);
    unsigned r = u + 0x7fffu + ((u >> 16) & 1u);   // RNE
    return (unsigned short)(r >> 16);
}
__device__ __forceinline__ float bf2f(unsigned short b) {
    return __uint_as_float(((unsigned)b) << 16);
}

// ---- init: x (f32) -> xb (bf16) ----
__global__ __launch_bounds__(256) void init_kernel(const float* __restrict__ x,
                                                   ushort* __restrict__ xb) {
    int i = blockIdx.x * 256 + threadIdx.x;           // per 4 elements
    if ((size_t)i * 4 >= (size_t)N_NODES * FEAT) return;
    float4 v = ((const float4*)x)[i];
    ((ushort4*)xb)[i] = make_ushort4(f2bf(v.x), f2bf(v.y), f2bf(v.z), f2bf(v.w));
}

// ---- weights f32 -> bf16, all layers at once ----
__global__ __launch_bounds__(256) void wconv_kernel(const float* __restrict__ Wl,
                                                    const float* __restrict__ Wr,
                                                    ushort* __restrict__ wlb,
                                                    ushort* __restrict__ wrb) {
    int i = blockIdx.x * 256 + threadIdx.x;           // per 4 elements
    if ((size_t)i * 4 >= (size_t)N_LAYERS * FEAT * FEAT) return;
    float4 a = ((const float4*)Wl)[i];
    float4 b = ((const float4*)Wr)[i];
    ((ushort4*)wlb)[i] = make_ushort4(f2bf(a.x), f2bf(a.y), f2bf(a.z), f2bf(a.w));
    ((ushort4*)wrb)[i] = make_ushort4(f2bf(b.x), f2bf(b.y), f2bf(b.z), f2bf(b.w));
}

// ================= CSR construction (counting sort by dst) =================

__global__ __launch_bounds__(256) void hist_kernel(const int* __restrict__ dst,
                                                   unsigned* __restrict__ degu) {
    int e = blockIdx.x * 256 + threadIdx.x;
    if (e < N_EDGES) atomicAdd(&degu[dst[e]], 1u);
}

__global__ __launch_bounds__(SCAN_B) void scan_blocks(const unsigned* __restrict__ degu,
                                                      unsigned* __restrict__ excl,
                                                      unsigned* __restrict__ bsum) {
    __shared__ unsigned tmp[SCAN_B];
    int i = blockIdx.x * SCAN_B + threadIdx.x;
    unsigned v = (i < N_NODES) ? degu[i] : 0u;
    tmp[threadIdx.x] = v;
    __syncthreads();
    for (int off = 1; off < SCAN_B; off <<= 1) {
        unsigned add = (threadIdx.x >= off) ? tmp[threadIdx.x - off] : 0u;
        __syncthreads();
        tmp[threadIdx.x] += add;
        __syncthreads();
    }
    if (i < N_NODES) excl[i] = tmp[threadIdx.x] - v;
    if (threadIdx.x == SCAN_B - 1) bsum[blockIdx.x] = tmp[SCAN_B - 1];
}

__global__ void scan_tops(unsigned* __restrict__ bsum, int nb) {
    unsigned run = 0;
    for (int b = 0; b < nb; ++b) { unsigned t = bsum[b]; bsum[b] = run; run += t; }
}

__global__ __launch_bounds__(256) void finalize_rowptr(const unsigned* __restrict__ excl,
                                                       const unsigned* __restrict__ bsum,
                                                       unsigned* __restrict__ rowptr,
                                                       unsigned* __restrict__ cursor) {
    int i = blockIdx.x * 256 + threadIdx.x;
    if (i < N_NODES) {
        unsigned v = excl[i] + bsum[i / SCAN_B];
        rowptr[i] = v;
        cursor[i] = v;
    }
    if (i == N_NODES) rowptr[N_NODES] = N_EDGES;
}

__global__ __launch_bounds__(256) void scatter_kernel(const int* __restrict__ ei,
                                                      unsigned* __restrict__ cursor,
                                                      unsigned* __restrict__ col) {
    int e = blockIdx.x * 256 + threadIdx.x;
    if (e >= N_EDGES) return;
    int d = ei[N_EDGES + e];
    unsigned p = atomicAdd(&cursor[d], 1u);
    col[p] = (unsigned)ei[e];
}

// ---- per-graph [start,end) bounds from sorted batch: boundary detection ----
__global__ __launch_bounds__(256) void bounds_kernel(const int* __restrict__ batch,
                                                     unsigned* __restrict__ gs,
                                                     unsigned* __restrict__ ge) {
    int i = blockIdx.x * 256 + threadIdx.x;
    if (i >= N_NODES) return;
    int g = batch[i];
    int gp = (i == 0) ? -1 : batch[i - 1];
    if (g != gp) gs[g] = (unsigned)i;
    int gn = (i == N_NODES - 1) ? -1 : batch[i + 1];
    if (g != gn) ge[g] = (unsigned)(i + 1);
}

// ============================================================================
// Fused layer kernel:
//   mean = CSR-mean-gather(xb)        [into LDS, GEMM-swizzled bf16]
//   xbn  = bf16( relu([mean|xb] @ [Wl|Wr]^T + bl) + xb )
// Block: 128 nodes x 256 cols, 8 waves (2 row-halves x 4 col-quarters).
// LDS: mean 64 KB (8 k-tiles of [128][32] packed 2-rows/128B-line, XOR swizzle
//      byte ^= (line&7)<<4) + B tile 16 KB (same layout). 80 KB -> 2 blocks/CU.
// B is reg-staged (global->reg during compute kt-1, reg->ds_write at phase top)
// so no global_load_lds / vmcnt-drain coupling. A1(x) frags read direct global.
// ============================================================================
__global__ __launch_bounds__(512, 4) void gemm_kernel(const unsigned* __restrict__ rowptr,
                                                      const unsigned* __restrict__ col,
                                                      const ushort* __restrict__ xb,   // cur x, bf16
                                                      const ushort* __restrict__ B0,   // Wl slice [256][256]
                                                      const ushort* __restrict__ B1,   // Wr slice
                                                      const float* __restrict__ bias,  // bl slice [256]
                                                      ushort* __restrict__ xbn) {      // next-layer x
    __shared__ ushort Ms[8 * 4096];   // mean: 8 k-tiles x 8 KB = 64 KB
    __shared__ ushort Bs[8192];       // B k-tile: 16 KB

    const int tid  = threadIdx.x;
    const int lane = tid & 63;
    const int wid  = tid >> 6;          // 0..7
    const int wr   = wid >> 2;          // 0..1  (row half of 128)
    const int wc   = wid & 3;           // 0..3  (col quarter of 256)
    const int row0 = blockIdx.x * 128;

    // ---- B reg-staging addresses (kt-invariant) ----
    const int bL  = tid >> 2;           // LDS line 0..127 (2 rows each)
    const int bw0 = (tid & 3) << 5;     // byte offset within 128B line (chunk 0)
    // chunk c: w = bw0 + c*16; global row = 2*bL + (w>>6); elem = (w&63)>>1
    // lds byte = bL*128 + (w ^ ((bL&7)<<4))

    v8s breg0, breg1;
    #define LOADB(kt) do {                                                        \
        const ushort* Bsrc = ((kt) < 8) ? B0 : B1;                                \
        const int kb = ((kt) & 7) * 32;                                           \
        breg0 = *(const v8s*)(Bsrc + (size_t)(2 * bL + (bw0 >> 6)) * FEAT + kb + ((bw0 & 63) >> 1)); \
        const int w1 = bw0 + 16;                                                  \
        breg1 = *(const v8s*)(Bsrc + (size_t)(2 * bL + (w1 >> 6)) * FEAT + kb + ((w1 & 63) >> 1));   \
    } while (0)

    #define WRITEB() do {                                                         \
        *(v8s*)((char*)Bs + bL * 128 + ((bw0)      ^ ((bL & 7) << 4))) = breg0;   \
        *(v8s*)((char*)Bs + bL * 128 + ((bw0 + 16) ^ ((bL & 7) << 4))) = breg1;   \
    } while (0)

    LOADB(0);   // lands during gather

    // ======================= gather: mean -> Ms =======================
    {
        const int h   = lane >> 5;        // half-wave: node parity
        const int l32 = lane & 31;        // 8 feats per lane (ushort8)
        #pragma unroll 1
        for (int p = 0; p < 8; ++p) {
            const int rl = wid * 16 + p * 2 + h;     // local row 0..127
            const int node = row0 + rl;
            unsigned s = 0, e = 0;
            if (node < N_NODES) { s = rowptr[node]; e = rowptr[node + 1]; }
            float a0=0.f,a1=0.f,a2=0.f,a3=0.f,a4=0.f,a5=0.f,a6=0.f,a7=0.f;
            #pragma unroll 1
            for (unsigned base = s; base < e; base += 32) {
                unsigned idx = base + (unsigned)l32;
                int cv = (idx < e) ? (int)col[idx] : 0;
                int n = (int)(e - base); n = n > 32 ? 32 : n;
                #pragma unroll 1
                for (int j = 0; j < n; ++j) {
                    unsigned src = (unsigned)__shfl(cv, (h << 5) + j);
                    v8s v = *(const v8s*)(xb + (size_t)src * FEAT + l32 * 8);
                    a0 += bf2f((ushort)v[0]); a1 += bf2f((ushort)v[1]);
                    a2 += bf2f((ushort)v[2]); a3 += bf2f((ushort)v[3]);
                    a4 += bf2f((ushort)v[4]); a5 += bf2f((ushort)v[5]);
                    a6 += bf2f((ushort)v[6]); a7 += bf2f((ushort)v[7]);
                }
            }
            float r = 1.0f / fmaxf((float)(e - s), 1.0f);
            v8s o;
            o[0]=(short)f2bf(a0*r); o[1]=(short)f2bf(a1*r);
            o[2]=(short)f2bf(a2*r); o[3]=(short)f2bf(a3*r);
            o[4]=(short)f2bf(a4*r); o[5]=(short)f2bf(a5*r);
            o[6]=(short)f2bf(a6*r); o[7]=(short)f2bf(a7*r);
            const int t8   = l32 >> 2;            // k-tile of these 8 feats
            const int cb   = (l32 & 3) << 4;      // byte col within 64B row
            const int line = rl >> 1, half = rl & 1;
            *(v8s*)((char*)Ms + t8 * 8192 + line * 128 +
                    (((half << 6) + cb) ^ ((line & 7) << 4))) = o;
        }
    }
    __syncthreads();   // mean complete (also drains breg(0) loads — gather is long)

    // ======================= K-loop =======================
    v4f acc[4][4] = {};
    const int fr  = lane & 15;
    const int cbk = (lane >> 4) << 4;   // frag byte col within 64B row

    #define FRAG(basePtr, row) \
        (*(const v8s*)((const char*)(basePtr) + (((row) >> 1) * 128 + \
            ((((row) & 1) << 6) + cbk) ^ ((((row) >> 1) & 7) << 4))))

    int arow[4];
    #pragma unroll
    for (int i = 0; i < 4; ++i) {
        int r = row0 + wr * 64 + i * 16 + fr;
        arow[i] = r < N_NODES ? r : N_NODES - 1;
    }

    #pragma unroll 1
    for (int kt = 0; kt < 16; ++kt) {
        WRITEB();                 // Bs <- bregs(kt); previous readers done (barrier below)
        __syncthreads();          // ds_writes visible to all
        if (kt < 15) LOADB(kt + 1);   // lands during compute; drained by phase-end barrier
        v8s a[4], b[4];
        if (kt < 8) {
            #pragma unroll
            for (int i = 0; i < 4; ++i)
                a[i] = FRAG((char*)Ms + kt * 8192, wr * 64 + i * 16 + fr);
        } else {
            const int ke = (kt & 7) * 32 + ((lane >> 4) << 3);
            #pragma unroll
            for (int i = 0; i < 4; ++i)
                a[i] = *(const v8s*)(xb + (size_t)arow[i] * FEAT + ke);
        }
        #pragma unroll
        for (int j = 0; j < 4; ++j)
            b[j] = FRAG(Bs, wc * 64 + j * 16 + fr);
        #pragma unroll
        for (int i = 0; i < 4; ++i)
            #pragma unroll
            for (int j = 0; j < 4; ++j)
                acc[i][j] = __builtin_amdgcn_mfma_f32_16x16x32_bf16(a[i], b[j], acc[i][j], 0, 0, 0);
        __syncthreads();          // all waves done reading Bs; bregs(kt+1) drained
    }

    // epilogue: C/D layout col=lane&15, row=(lane>>4)*4+reg
    const int orow = (lane >> 4) * 4;
    const int ocol = lane & 15;
    #pragma unroll
    for (int j = 0; j < 4; ++j) {
        int colg = wc * 64 + j * 16 + ocol;
        float bv = bias[colg];
        #pragma unroll
        for (int i = 0; i < 4; ++i) {
            int rbase = row0 + wr * 64 + i * 16 + orow;
            #pragma unroll
            for (int r = 0; r < 4; ++r) {
                int row = rbase + r;
                if (row < N_NODES) {
                    size_t idx = (size_t)row * FEAT + colg;
                    float v = fmaxf(acc[i][j][r] + bv, 0.0f) + bf2f(xb[idx]);
                    xbn[idx] = f2bf(v);
                }
            }
        }
    }
    #undef LOADB
    #undef WRITEB
    #undef FRAG
}

// ---- per-graph per-feature online softmax aggregation (bf16 input) ----
__global__ __launch_bounds__(256) void smax_kernel(const ushort* __restrict__ xb,
                                                   const unsigned* __restrict__ gs,
                                                   const unsigned* __restrict__ ge,
                                                   const float* __restrict__ t,
                                                   float* __restrict__ out) {
    int g = blockIdx.x;
    int f = threadIdx.x;
    unsigned s = gs[g], e = ge[g];
    float tv = t[0];
    float m = -INFINITY, den = 0.f, acc = 0.f;
    if (s < e) {
        for (unsigned n = s; n < e; ++n) {
            float xv = bf2f(xb[(size_t)n * FEAT + f]);
            float sc = tv * xv;
            float mn = fmaxf(m, sc);
            float scale = expf(m - mn);     // 0 on first iter (m = -inf)
            float w = expf(sc - mn);
            den = den * scale + w;
            acc = acc * scale + w * xv;
            m = mn;
        }
        out[(size_t)g * FEAT + f] = acc / fmaxf(den, 1e-16f);
    } else {
        out[(size_t)g * FEAT + f] = 0.f;   // empty segment -> 0 per reference
    }
}

extern "C" void kernel_launch(void* const* d_in, const int* in_sizes, int n_in,
                              void* d_out, int out_size, void* d_ws, size_t ws_size,
                              hipStream_t stream) {
    const float* x     = (const float*)d_in[0];
    const int*   ei    = (const int*)d_in[1];    // [2, E]: row0=src, row1=dst
    const int*   batch = (const int*)d_in[2];
    const float* Wl    = (const float*)d_in[3];  // [L, F, F]
    const float* bl    = (const float*)d_in[4];  // [L, F]
    const float* Wr    = (const float*)d_in[5];  // [L, F, F]
    const float* t     = (const float*)d_in[6];  // [1]
    float* out = (float*)d_out;

    const size_t NF2 = (size_t)N_NODES * FEAT * 2;   // 51,200,000
    const size_t WSZ = (size_t)N_LAYERS * FEAT * FEAT * 2;

    char* ws = (char*)d_ws;
    size_t off = 0;
    ushort* xb0   = (ushort*)(ws + off); off += NF2;
    ushort* xb1   = (ushort*)(ws + off); off += NF2;
    ushort* wlb   = (ushort*)(ws + off); off += WSZ;
    ushort* wrb   = (ushort*)(ws + off); off += WSZ;
    unsigned* degu   = (unsigned*)(ws + off); off += (size_t)N_NODES * 4;
    unsigned* excl   = (unsigned*)(ws + off); off += (size_t)N_NODES * 4;
    unsigned* bsum   = (unsigned*)(ws + off); off += 128 * 4;
    unsigned* rowptr = (unsigned*)(ws + off); off += (size_t)(N_NODES + 1) * 4;
    unsigned* cursor = (unsigned*)(ws + off); off += (size_t)N_NODES * 4;
    unsigned* col    = (unsigned*)(ws + off); off += (size_t)N_EDGES * 4;
    unsigned* gs     = (unsigned*)(ws + off); off += (size_t)N_GRAPHS * 4;
    unsigned* ge     = (unsigned*)(ws + off); off += (size_t)N_GRAPHS * 4;

    hipMemsetAsync(degu, 0, (size_t)N_NODES * 4, stream);
    hipMemsetAsync(gs, 0xFF, (size_t)N_GRAPHS * 4, stream);
    hipMemsetAsync(ge, 0, (size_t)N_GRAPHS * 4, stream);

    init_kernel<<<(N_NODES * FEAT / 4 + 255) / 256, 256, 0, stream>>>(x, xb0);
    wconv_kernel<<<(N_LAYERS * FEAT * FEAT / 4 + 255) / 256, 256, 0, stream>>>(Wl, Wr, wlb, wrb);

    // CSR build
    const int NB_SCAN = (N_NODES + SCAN_B - 1) / SCAN_B;   // 98
    hist_kernel<<<(N_EDGES + 255) / 256, 256, 0, stream>>>(ei + N_EDGES, degu);
    scan_blocks<<<NB_SCAN, SCAN_B, 0, stream>>>(degu, excl, bsum);
    scan_tops<<<1, 1, 0, stream>>>(bsum, NB_SCAN);
    finalize_rowptr<<<(N_NODES + 256) / 256, 256, 0, stream>>>(excl, bsum, rowptr, cursor);
    scatter_kernel<<<(N_EDGES + 255) / 256, 256, 0, stream>>>(ei, cursor, col);

    bounds_kernel<<<(N_NODES + 255) / 256, 256, 0, stream>>>(batch, gs, ge);

    ushort* cur = xb0;
    ushort* nxt = xb1;
    for (int l = 0; l < N_LAYERS; ++l) {
        gemm_kernel<<<dim3((N_NODES + 127) / 128), 512, 0, stream>>>(
            rowptr, col, cur,
            wlb + (size_t)l * FEAT * FEAT, wrb + (size_t)l * FEAT * FEAT,
            bl + (size_t)l * FEAT, nxt);
        ushort* tmp = cur; cur = nxt; nxt = tmp;
    }

    smax_kernel<<<N_GRAPHS, 256, 0, stream>>>(cur, gs, ge, t, out);
}